// Round 3
// baseline (1228.082 us; speedup 1.0000x reference)
//
#include <hip/hip_runtime.h>
#include <cstdint>
#include <cstddef>

// ---------------------------------------------------------------------------
// CausalSelfAttention, B=4 T=2048 C=2048 H=16 D=128, fp32 in/out.
// cvt(fp32->bf16) -> gemm_qkv (qkv + fused rope; Q,K (B,H,T,D), V^T (B,H,D,T))
// -> fattn (flash, 128-row q-tiles, async LDS staging, LPT order)
// -> gemm_proj (fp32 out)
// Workspace layout (bytes):
//   0         Wq_b   (6144x2048 bf16)  25165824
//   25165824  Wp_b   (2048x2048 bf16)   8388608
//   33554432  x_b    (8192x2048 bf16)  33554432
//   67108864  Qb     (B,H,T,D bf16)    33554432
//   100663296 Kb     (B,H,T,D bf16)    33554432
//   134217728 Vt     (B,H,D,T bf16)    33554432
//   167772160 Yb     (8192x2048 bf16)  33554432
// ---------------------------------------------------------------------------

typedef unsigned short u16;
typedef u16    u16x8 __attribute__((ext_vector_type(8)));
typedef __bf16 bf16x8 __attribute__((ext_vector_type(8)));
typedef float  f32x4 __attribute__((ext_vector_type(4)));

#define MFMA16(a, b, c) __builtin_amdgcn_mfma_f32_16x16x32_bf16( \
    __builtin_bit_cast(bf16x8, (a)), __builtin_bit_cast(bf16x8, (b)), (c), 0, 0, 0)

static __device__ __forceinline__ u16 f2b(float f) {
  unsigned u = __builtin_bit_cast(unsigned, f);
  unsigned r = (u + 0x7FFFu + ((u >> 16) & 1u)) >> 16;   // RNE
  return (u16)r;
}

// async global->LDS, 16B per lane; lds dest = (wave-uniform base) + lane*16
static __device__ __forceinline__ void gld_lds16(const void* g, void* l) {
  __builtin_amdgcn_global_load_lds(
      (__attribute__((address_space(1))) unsigned int*)(void*)(g),
      (__attribute__((address_space(3))) unsigned int*)(l),
      16, 0, 0);
}

// ---------------------------------------------------------------------------
// fp32 -> bf16 conversion, 8 elements/thread
// ---------------------------------------------------------------------------
__global__ __launch_bounds__(256) void cvt_bf16(const float4* __restrict__ src,
                                                u16x8* __restrict__ dst, int n8) {
  int i = blockIdx.x * 256 + threadIdx.x;
  if (i >= n8) return;
  float4 a = src[i * 2], b = src[i * 2 + 1];
  u16x8 o;
  o[0] = f2b(a.x); o[1] = f2b(a.y); o[2] = f2b(a.z); o[3] = f2b(a.w);
  o[4] = f2b(b.x); o[5] = f2b(b.y); o[6] = f2b(b.z); o[7] = f2b(b.w);
  dst[i] = o;
}

// ---------------------------------------------------------------------------
// GEMM1: qkv = x_b @ W_attn^T with FUSED ROPE on Q,K in the epilogue.
// 128x128 tile, BK=64, 4 waves (2x2), each wave 4x4 of 16x16x32 MFMAs.
// Epilogue scatters: Q (B,H,T,D) roped, K (B,H,T,D) roped, V^T (B,H,D,T).
// Each 128-col block span covers exactly one section (Q/K/V) and one head.
// ---------------------------------------------------------------------------
__global__ __launch_bounds__(256) void gemm_qkv(
    const u16* __restrict__ A, const u16* __restrict__ Bw,
    const float* __restrict__ freqs, int K,
    u16* __restrict__ Qp, u16* __restrict__ Kp, u16* __restrict__ Vp) {
  __shared__ alignas(16) u16 lA[128 * 64];
  __shared__ alignas(16) u16 lB[128 * 64];
  const int tid = threadIdx.x;
  const int lane = tid & 63, wv = tid >> 6;
  const int quad = lane >> 4, col = lane & 15;
  const int wm = wv & 1, wn = wv >> 1;
  const int m0 = blockIdx.y * 128, n0 = blockIdx.x * 128;

  f32x4 acc[4][4];
#pragma unroll
  for (int i = 0; i < 4; ++i)
#pragma unroll
    for (int j = 0; j < 4; ++j) acc[i][j] = (f32x4){0.f, 0.f, 0.f, 0.f};

  for (int k0 = 0; k0 < K; k0 += 64) {
    __syncthreads();
#pragma unroll
    for (int u = 0; u < 4; ++u) {
      int ci = ((wv * 4 + u) << 6) + lane;  // 0..1023
      int m = ci >> 3, c = ci & 7;
      int sc = c ^ (m & 7);
      gld_lds16(A + (size_t)(m0 + m) * K + k0 + (sc << 3), lA + ((size_t)(wv * 4 + u) << 9));
      gld_lds16(Bw + (size_t)(n0 + m) * K + k0 + (sc << 3), lB + ((size_t)(wv * 4 + u) << 9));
    }
    __syncthreads();
#pragma unroll
    for (int t = 0; t < 2; ++t) {
      u16x8 af[4], bf[4];
#pragma unroll
      for (int i = 0; i < 4; ++i) {
        int m = wm * 64 + i * 16 + col;
        af[i] = *(const u16x8*)&lA[(m * 8 + (((t << 2) | quad) ^ (m & 7))) * 8];
        int n = wn * 64 + i * 16 + col;
        bf[i] = *(const u16x8*)&lB[(n * 8 + (((t << 2) | quad) ^ (n & 7))) * 8];
      }
#pragma unroll
      for (int i = 0; i < 4; ++i)
#pragma unroll
        for (int j = 0; j < 4; ++j) acc[i][j] = MFMA16(af[i], bf[j], acc[i][j]);
    }
  }

  // epilogue: C/D layout row = quad*4+reg, col = lane&15. Block-uniform section.
  const int which = n0 >> 11;          // 0=Q 1=K 2=V
  const int h = (n0 & 2047) >> 7;
  if (which == 2) {
#pragma unroll
    for (int i = 0; i < 4; ++i) {
      int mg = m0 + wm * 64 + i * 16 + quad * 4;
#pragma unroll
      for (int j = 0; j < 4; ++j) {
        int d = wn * 64 + j * 16 + col;
#pragma unroll
        for (int r = 0; r < 4; ++r) {
          int m = mg + r;
          int b = m >> 11, t = m & 2047;
          size_t off = (((size_t)(b * 16 + h) * 128 + d) << 11) | (size_t)t;
          Vp[off] = f2b(acc[i][j][r]);
        }
      }
    }
  } else {
    u16* dst = (which == 0) ? Qp : Kp;
#pragma unroll
    for (int j = 0; j < 4; ++j) {
      int dd = wn * 64 + j * 16 + col;
      int jj = dd >> 1;
      bool even = (dd & 1) == 0;
      float fr = freqs[jj];
      int dout = even ? jj : jj + 64;
#pragma unroll
      for (int i = 0; i < 4; ++i) {
        int mg = m0 + wm * 64 + i * 16 + quad * 4;
#pragma unroll
        for (int r = 0; r < 4; ++r) {
          float own = acc[i][j][r];
          float par = __shfl_xor(own, 1);
          int m = mg + r;
          int b = m >> 11, t = m & 2047;
          float theta = (float)t * fr;                       // matches ref fp32 theta
          float rev = theta * 0.15915494309189535f;          // /2pi
          rev -= floorf(rev);
          float s = __builtin_amdgcn_sinf(rev);              // sin(2*pi*rev)
          float c = __builtin_amdgcn_cosf(rev);
          float outv = even ? (own * c - par * s) : (par * s + own * c);
          size_t off = ((((size_t)(b * 16 + h)) << 11 | (size_t)t) << 7) | (size_t)dout;
          dst[off] = f2b(outv);
        }
      }
    }
  }
}

// ---------------------------------------------------------------------------
// GEMM2: out = y @ W_proj^T, fp32 out. Same 128x128 structure.
// ---------------------------------------------------------------------------
__global__ __launch_bounds__(256) void gemm_proj(
    const u16* __restrict__ A, const u16* __restrict__ Bw,
    int N, int K, float* __restrict__ out) {
  __shared__ alignas(16) u16 lA[128 * 64];
  __shared__ alignas(16) u16 lB[128 * 64];
  const int tid = threadIdx.x;
  const int lane = tid & 63, wv = tid >> 6;
  const int quad = lane >> 4, col = lane & 15;
  const int wm = wv & 1, wn = wv >> 1;
  const int m0 = blockIdx.y * 128, n0 = blockIdx.x * 128;

  f32x4 acc[4][4];
#pragma unroll
  for (int i = 0; i < 4; ++i)
#pragma unroll
    for (int j = 0; j < 4; ++j) acc[i][j] = (f32x4){0.f, 0.f, 0.f, 0.f};

  for (int k0 = 0; k0 < K; k0 += 64) {
    __syncthreads();
#pragma unroll
    for (int u = 0; u < 4; ++u) {
      int ci = ((wv * 4 + u) << 6) + lane;
      int m = ci >> 3, c = ci & 7;
      int sc = c ^ (m & 7);
      gld_lds16(A + (size_t)(m0 + m) * K + k0 + (sc << 3), lA + ((size_t)(wv * 4 + u) << 9));
      gld_lds16(Bw + (size_t)(n0 + m) * K + k0 + (sc << 3), lB + ((size_t)(wv * 4 + u) << 9));
    }
    __syncthreads();
#pragma unroll
    for (int t = 0; t < 2; ++t) {
      u16x8 af[4], bf[4];
#pragma unroll
      for (int i = 0; i < 4; ++i) {
        int m = wm * 64 + i * 16 + col;
        af[i] = *(const u16x8*)&lA[(m * 8 + (((t << 2) | quad) ^ (m & 7))) * 8];
        int n = wn * 64 + i * 16 + col;
        bf[i] = *(const u16x8*)&lB[(n * 8 + (((t << 2) | quad) ^ (n & 7))) * 8];
      }
#pragma unroll
      for (int i = 0; i < 4; ++i)
#pragma unroll
        for (int j = 0; j < 4; ++j) acc[i][j] = MFMA16(af[i], bf[j], acc[i][j]);
    }
  }
#pragma unroll
  for (int i = 0; i < 4; ++i) {
    int mg = m0 + wm * 64 + i * 16 + quad * 4;
#pragma unroll
    for (int j = 0; j < 4; ++j) {
      int ng = n0 + wn * 64 + j * 16 + col;
#pragma unroll
      for (int r = 0; r < 4; ++r) out[(size_t)(mg + r) * N + ng] = acc[i][j][r];
    }
  }
}

// ---------------------------------------------------------------------------
// Flash attention, causal. One block per (128 q rows, b*h); 4 waves x 32 rows
// (m=2 tiles of 16). BC=64 kv rows/iter, async global_load_lds staging.
// Heavy q-tiles dispatched first (LPT). LDS 48KB -> 3 blocks/CU.
// ---------------------------------------------------------------------------
__global__ __launch_bounds__(256, 3) void fattn(
    const u16* __restrict__ Qb, const u16* __restrict__ Kb, const u16* __restrict__ Vt,
    u16* __restrict__ Yb) {
  __shared__ alignas(16) u16 lK[64 * 128];    // [kc][d], chunk16 xor row&15
  __shared__ alignas(16) u16 lVt[128 * 64];   // [d][kc], chunk8 xor row&7
  __shared__ alignas(16) u16 lP[4][32 * 64];  // per-wave [qr][kc], chunk8 xor row&7

  const int tid = threadIdx.x;
  const int lane = tid & 63, wv = tid >> 6;
  const int quad = lane >> 4, col = lane & 15;
  const int qblk = 15 - blockIdx.x;            // heavy-first
  const int bh = blockIdx.y;
  const int b = bh >> 4, h = bh & 15;
  const size_t base = (size_t)bh << 18;        // * 2048 * 128
  const int qr0 = qblk * 128 + wv * 32;        // wave's first q row
  const float kcomb = 0.08838834764831845f * 1.4426950408889634f;  // 1/sqrt(D)*log2e

  u16x8 qf[2][4];
#pragma unroll
  for (int m = 0; m < 2; ++m)
#pragma unroll
    for (int t = 0; t < 4; ++t)
      qf[m][t] = *(const u16x8*)(Qb + base + (size_t)(qr0 + m * 16 + col) * 128 + t * 32 + quad * 8);

  f32x4 mrow[2], lrow[2], o[2][8];
#pragma unroll
  for (int m = 0; m < 2; ++m) {
    mrow[m] = (f32x4){-1e30f, -1e30f, -1e30f, -1e30f};
    lrow[m] = (f32x4){0.f, 0.f, 0.f, 0.f};
#pragma unroll
    for (int dt = 0; dt < 8; ++dt) o[m][dt] = (f32x4){0.f, 0.f, 0.f, 0.f};
  }

  const int nkt = 2 * qblk + 2;
#pragma unroll 1
  for (int kt = 0; kt < nkt; ++kt) {
    __syncthreads();
    // stage K tile (64 x 128)
#pragma unroll
    for (int u = 0; u < 4; ++u) {
      int row = wv * 16 + u * 4 + (lane >> 4);
      int sc = (lane & 15) ^ (row & 15);
      gld_lds16(Kb + base + (size_t)(kt * 64 + row) * 128 + (sc << 3),
                lK + (size_t)(wv * 16 + u * 4) * 128);
    }
    // stage V^T tile (128 x 64)
#pragma unroll
    for (int u = 0; u < 4; ++u) {
      int row = wv * 32 + u * 8 + (lane >> 3);
      int sc = (lane & 7) ^ (row & 7);
      gld_lds16(Vt + base + (size_t)row * 2048 + kt * 64 + (sc << 3),
                lVt + (size_t)(wv * 32 + u * 8) * 64);
    }
    __syncthreads();

    bool act = (kt * 64) <= (qr0 + 31);
    if (act) {
#pragma unroll
      for (int m = 0; m < 2; ++m) {
        f32x4 sv[4];
#pragma unroll
        for (int nt = 0; nt < 4; ++nt) {
          f32x4 s = (f32x4){0.f, 0.f, 0.f, 0.f};
#pragma unroll
          for (int t = 0; t < 4; ++t) {
            int krow = nt * 16 + col;
            u16x8 kf = *(const u16x8*)&lK[krow * 128 + ((((t << 2) | quad) ^ (krow & 15)) << 3)];
            s = MFMA16(qf[m][t], kf, s);
          }
          sv[nt] = s;
        }
#pragma unroll
        for (int nt = 0; nt < 4; ++nt)
#pragma unroll
          for (int r = 0; r < 4; ++r) sv[nt][r] *= kcomb;
        if (kt >= 2 * qblk) {  // diagonal tiles only
#pragma unroll
          for (int nt = 0; nt < 4; ++nt) {
            int cg = kt * 64 + nt * 16 + col;
#pragma unroll
            for (int r = 0; r < 4; ++r)
              if (cg > qr0 + m * 16 + quad * 4 + r) sv[nt][r] = -1e30f;
          }
        }
        // row max over nt and 16 lanes
        f32x4 mx = sv[0];
#pragma unroll
        for (int nt = 1; nt < 4; ++nt)
#pragma unroll
          for (int r = 0; r < 4; ++r) mx[r] = fmaxf(mx[r], sv[nt][r]);
#pragma unroll
        for (int off = 1; off < 16; off <<= 1)
#pragma unroll
          for (int r = 0; r < 4; ++r) mx[r] = fmaxf(mx[r], __shfl_xor(mx[r], off));
        f32x4 alpha;
#pragma unroll
        for (int r = 0; r < 4; ++r) {
          float mn = fmaxf(mrow[m][r], mx[r]);
          alpha[r] = exp2f(mrow[m][r] - mn);
          mrow[m][r] = mn;
        }
        f32x4 ps = (f32x4){0.f, 0.f, 0.f, 0.f};
#pragma unroll
        for (int nt = 0; nt < 4; ++nt)
#pragma unroll
          for (int r = 0; r < 4; ++r) {
            float pe = exp2f(sv[nt][r] - mrow[m][r]);
            ps[r] += pe;
            int row = m * 16 + quad * 4 + r;
            int ch = ((nt << 1) | (col >> 3)) ^ (row & 7);
            lP[wv][row * 64 + (ch << 3) + (col & 7)] = f2b(pe);
          }
#pragma unroll
        for (int off = 1; off < 16; off <<= 1)
#pragma unroll
          for (int r = 0; r < 4; ++r) ps[r] += __shfl_xor(ps[r], off);
#pragma unroll
        for (int r = 0; r < 4; ++r) lrow[m][r] = lrow[m][r] * alpha[r] + ps[r];
#pragma unroll
        for (int dt = 0; dt < 8; ++dt)
#pragma unroll
          for (int r = 0; r < 4; ++r) o[m][dt][r] *= alpha[r];
      }
      // PV: o[m] += P(16x64) x V^T
#pragma unroll
      for (int t = 0; t < 2; ++t) {
        u16x8 pf[2];
#pragma unroll
        for (int m = 0; m < 2; ++m) {
          int prow = m * 16 + col;
          pf[m] = *(const u16x8*)&lP[wv][prow * 64 + ((((t << 2) | quad) ^ (prow & 7)) << 3)];
        }
#pragma unroll
        for (int dt = 0; dt < 8; ++dt) {
          int drow = dt * 16 + col;
          u16x8 vf = *(const u16x8*)&lVt[drow * 64 + ((((t << 2) | quad) ^ (drow & 7)) << 3)];
          o[0][dt] = MFMA16(pf[0], vf, o[0][dt]);
          o[1][dt] = MFMA16(pf[1], vf, o[1][dt]);
        }
      }
    }
  }  // kt

  // normalize + write Y (B*T, C) bf16
#pragma unroll
  for (int m = 0; m < 2; ++m) {
    f32x4 inv;
#pragma unroll
    for (int r = 0; r < 4; ++r) inv[r] = 1.0f / lrow[m][r];
#pragma unroll
    for (int dt = 0; dt < 8; ++dt)
#pragma unroll
      for (int r = 0; r < 4; ++r) {
        float y = o[m][dt][r] * inv[r];
        int q = qr0 + m * 16 + quad * 4 + r;
        Yb[((size_t)(b * 2048 + q)) * 2048 + h * 128 + dt * 16 + col] = f2b(y);
      }
  }
}

// ---------------------------------------------------------------------------
extern "C" void kernel_launch(void* const* d_in, const int* in_sizes, int n_in,
                              void* d_out, int out_size, void* d_ws, size_t ws_size,
                              hipStream_t stream) {
  (void)in_sizes; (void)n_in; (void)out_size; (void)ws_size;
  const float* x     = (const float*)d_in[0];
  const float* freqs = (const float*)d_in[1];
  const float* Wattn = (const float*)d_in[2];
  const float* Wproj = (const float*)d_in[3];
  float* out = (float*)d_out;
  char* ws = (char*)d_ws;

  u16* Wq_b = (u16*)(ws + 0);
  u16* Wp_b = (u16*)(ws + 25165824);
  u16* x_b  = (u16*)(ws + 33554432);
  u16* Qb   = (u16*)(ws + 67108864);
  u16* Kb   = (u16*)(ws + 100663296);
  u16* Vt   = (u16*)(ws + 134217728);
  u16* Yb   = (u16*)(ws + 167772160);

  cvt_bf16<<<6144, 256, 0, stream>>>((const float4*)Wattn, (u16x8*)Wq_b, 12582912 / 8);
  cvt_bf16<<<2048, 256, 0, stream>>>((const float4*)Wproj, (u16x8*)Wp_b, 4194304 / 8);
  cvt_bf16<<<8192, 256, 0, stream>>>((const float4*)x, (u16x8*)x_b, 16777216 / 8);

  gemm_qkv<<<dim3(48, 64), 256, 0, stream>>>(x_b, Wq_b, freqs, 2048, Qb, Kb, Vt);
  fattn<<<dim3(16, 64), 256, 0, stream>>>(Qb, Kb, Vt, Yb);
  gemm_proj<<<dim3(16, 64), 256, 0, stream>>>(Yb, Wp_b, 2048, 2048, out);
}

// Round 4
// 673.565 us; speedup vs baseline: 1.8233x; 1.8233x over previous
//
#include <hip/hip_runtime.h>
#include <cstdint>
#include <cstddef>

// ---------------------------------------------------------------------------
// CausalSelfAttention, B=4 T=2048 C=2048 H=16 D=128, fp32 in/out.
// cvt(fp32->bf16) -> gemm_qkv (qkv + fused rope; Q,K (B,H,T,D), V^T TILED
// (B,H, T/64, D, 64) 16KB-contiguous tiles) -> fattn (flash, paired q-tiles,
// 8 waves/block, async contiguous LDS staging) -> gemm_proj (fp32 out)
// Workspace layout (bytes):
//   0         Wq_b   (6144x2048 bf16)  25165824
//   25165824  Wp_b   (2048x2048 bf16)   8388608
//   33554432  x_b    (8192x2048 bf16)  33554432
//   67108864  Qb     (B,H,T,D bf16)    33554432
//   100663296 Kb     (B,H,T,D bf16)    33554432
//   134217728 Vt     tiled (B,H,32,128,64) bf16  33554432
//   167772160 Yb     (8192x2048 bf16)  33554432
// ---------------------------------------------------------------------------

typedef unsigned short u16;
typedef u16    u16x8 __attribute__((ext_vector_type(8)));
typedef __bf16 bf16x8 __attribute__((ext_vector_type(8)));
typedef float  f32x4 __attribute__((ext_vector_type(4)));

#define MFMA16(a, b, c) __builtin_amdgcn_mfma_f32_16x16x32_bf16( \
    __builtin_bit_cast(bf16x8, (a)), __builtin_bit_cast(bf16x8, (b)), (c), 0, 0, 0)

static __device__ __forceinline__ u16 f2b(float f) {
  unsigned u = __builtin_bit_cast(unsigned, f);
  unsigned r = (u + 0x7FFFu + ((u >> 16) & 1u)) >> 16;   // RNE
  return (u16)r;
}

// async global->LDS, 16B per lane; lds dest = (wave-uniform base) + lane*16
static __device__ __forceinline__ void gld_lds16(const void* g, void* l) {
  __builtin_amdgcn_global_load_lds(
      (__attribute__((address_space(1))) unsigned int*)(void*)(g),
      (__attribute__((address_space(3))) unsigned int*)(l),
      16, 0, 0);
}

// ---------------------------------------------------------------------------
// fp32 -> bf16 conversion, 8 elements/thread
// ---------------------------------------------------------------------------
__global__ __launch_bounds__(256) void cvt_bf16(const float4* __restrict__ src,
                                                u16x8* __restrict__ dst, int n8) {
  int i = blockIdx.x * 256 + threadIdx.x;
  if (i >= n8) return;
  float4 a = src[i * 2], b = src[i * 2 + 1];
  u16x8 o;
  o[0] = f2b(a.x); o[1] = f2b(a.y); o[2] = f2b(a.z); o[3] = f2b(a.w);
  o[4] = f2b(b.x); o[5] = f2b(b.y); o[6] = f2b(b.z); o[7] = f2b(b.w);
  dst[i] = o;
}

// ---------------------------------------------------------------------------
// GEMM1: qkv = x_b @ W_attn^T with FUSED ROPE on Q,K in the epilogue.
// 128x128 tile, BK=64, 4 waves (2x2), each wave 4x4 of 16x16x32 MFMAs.
// Epilogue: Q (B,H,T,D) roped, K (B,H,T,D) roped, V^T tiled (B,H,kt,D,64).
// ---------------------------------------------------------------------------
__global__ __launch_bounds__(256) void gemm_qkv(
    const u16* __restrict__ A, const u16* __restrict__ Bw,
    const float* __restrict__ freqs, int K,
    u16* __restrict__ Qp, u16* __restrict__ Kp, u16* __restrict__ Vp) {
  __shared__ alignas(16) u16 lA[128 * 64];
  __shared__ alignas(16) u16 lB[128 * 64];
  const int tid = threadIdx.x;
  const int lane = tid & 63, wv = tid >> 6;
  const int quad = lane >> 4, col = lane & 15;
  const int wm = wv & 1, wn = wv >> 1;
  const int m0 = blockIdx.y * 128, n0 = blockIdx.x * 128;

  f32x4 acc[4][4];
#pragma unroll
  for (int i = 0; i < 4; ++i)
#pragma unroll
    for (int j = 0; j < 4; ++j) acc[i][j] = (f32x4){0.f, 0.f, 0.f, 0.f};

  for (int k0 = 0; k0 < K; k0 += 64) {
    __syncthreads();
#pragma unroll
    for (int u = 0; u < 4; ++u) {
      int ci = ((wv * 4 + u) << 6) + lane;  // 0..1023
      int m = ci >> 3, c = ci & 7;
      int sc = c ^ (m & 7);
      gld_lds16(A + (size_t)(m0 + m) * K + k0 + (sc << 3), lA + ((size_t)(wv * 4 + u) << 9));
      gld_lds16(Bw + (size_t)(n0 + m) * K + k0 + (sc << 3), lB + ((size_t)(wv * 4 + u) << 9));
    }
    __syncthreads();
#pragma unroll
    for (int t = 0; t < 2; ++t) {
      u16x8 af[4], bf[4];
#pragma unroll
      for (int i = 0; i < 4; ++i) {
        int m = wm * 64 + i * 16 + col;
        af[i] = *(const u16x8*)&lA[(m * 8 + (((t << 2) | quad) ^ (m & 7))) * 8];
        int n = wn * 64 + i * 16 + col;
        bf[i] = *(const u16x8*)&lB[(n * 8 + (((t << 2) | quad) ^ (n & 7))) * 8];
      }
#pragma unroll
      for (int i = 0; i < 4; ++i)
#pragma unroll
        for (int j = 0; j < 4; ++j) acc[i][j] = MFMA16(af[i], bf[j], acc[i][j]);
    }
  }

  // epilogue: C/D layout row = quad*4+reg, col = lane&15. Block-uniform section.
  const int which = n0 >> 11;          // 0=Q 1=K 2=V
  const int h = (n0 & 2047) >> 7;
  if (which == 2) {
#pragma unroll
    for (int i = 0; i < 4; ++i) {
      int mg = m0 + wm * 64 + i * 16 + quad * 4;
#pragma unroll
      for (int j = 0; j < 4; ++j) {
        int d = wn * 64 + j * 16 + col;
#pragma unroll
        for (int r = 0; r < 4; ++r) {
          int m = mg + r;
          int b = m >> 11, t = m & 2047;
          // tiled V^T: [bh][t>>6][d][t&63], 16KB contiguous per kv-tile
          size_t off = ((((size_t)(b * 16 + h)) * 32 + (size_t)(t >> 6)) * 128 + (size_t)d) * 64
                       + (size_t)(t & 63);
          Vp[off] = f2b(acc[i][j][r]);
        }
      }
    }
  } else {
    u16* dst = (which == 0) ? Qp : Kp;
#pragma unroll
    for (int j = 0; j < 4; ++j) {
      int dd = wn * 64 + j * 16 + col;
      int jj = dd >> 1;
      bool even = (dd & 1) == 0;
      float fr = freqs[jj];
      int dout = even ? jj : jj + 64;
#pragma unroll
      for (int i = 0; i < 4; ++i) {
        int mg = m0 + wm * 64 + i * 16 + quad * 4;
#pragma unroll
        for (int r = 0; r < 4; ++r) {
          float own = acc[i][j][r];
          float par = __shfl_xor(own, 1);
          int m = mg + r;
          int b = m >> 11, t = m & 2047;
          float theta = (float)t * fr;                       // matches ref fp32 theta
          float rev = theta * 0.15915494309189535f;          // /2pi
          rev -= floorf(rev);
          float s = __builtin_amdgcn_sinf(rev);              // sin(2*pi*rev)
          float c = __builtin_amdgcn_cosf(rev);
          float outv = even ? (own * c - par * s) : (par * s + own * c);
          size_t off = ((((size_t)(b * 16 + h)) << 11 | (size_t)t) << 7) | (size_t)dout;
          dst[off] = f2b(outv);
        }
      }
    }
  }
}

// ---------------------------------------------------------------------------
// GEMM2: out = y @ W_proj^T, fp32 out. Same 128x128 structure.
// ---------------------------------------------------------------------------
__global__ __launch_bounds__(256) void gemm_proj(
    const u16* __restrict__ A, const u16* __restrict__ Bw,
    int N, int K, float* __restrict__ out) {
  __shared__ alignas(16) u16 lA[128 * 64];
  __shared__ alignas(16) u16 lB[128 * 64];
  const int tid = threadIdx.x;
  const int lane = tid & 63, wv = tid >> 6;
  const int quad = lane >> 4, col = lane & 15;
  const int wm = wv & 1, wn = wv >> 1;
  const int m0 = blockIdx.y * 128, n0 = blockIdx.x * 128;

  f32x4 acc[4][4];
#pragma unroll
  for (int i = 0; i < 4; ++i)
#pragma unroll
    for (int j = 0; j < 4; ++j) acc[i][j] = (f32x4){0.f, 0.f, 0.f, 0.f};

  for (int k0 = 0; k0 < K; k0 += 64) {
    __syncthreads();
#pragma unroll
    for (int u = 0; u < 4; ++u) {
      int ci = ((wv * 4 + u) << 6) + lane;
      int m = ci >> 3, c = ci & 7;
      int sc = c ^ (m & 7);
      gld_lds16(A + (size_t)(m0 + m) * K + k0 + (sc << 3), lA + ((size_t)(wv * 4 + u) << 9));
      gld_lds16(Bw + (size_t)(n0 + m) * K + k0 + (sc << 3), lB + ((size_t)(wv * 4 + u) << 9));
    }
    __syncthreads();
#pragma unroll
    for (int t = 0; t < 2; ++t) {
      u16x8 af[4], bf[4];
#pragma unroll
      for (int i = 0; i < 4; ++i) {
        int m = wm * 64 + i * 16 + col;
        af[i] = *(const u16x8*)&lA[(m * 8 + (((t << 2) | quad) ^ (m & 7))) * 8];
        int n = wn * 64 + i * 16 + col;
        bf[i] = *(const u16x8*)&lB[(n * 8 + (((t << 2) | quad) ^ (n & 7))) * 8];
      }
#pragma unroll
      for (int i = 0; i < 4; ++i)
#pragma unroll
        for (int j = 0; j < 4; ++j) acc[i][j] = MFMA16(af[i], bf[j], acc[i][j]);
    }
  }
#pragma unroll
  for (int i = 0; i < 4; ++i) {
    int mg = m0 + wm * 64 + i * 16 + quad * 4;
#pragma unroll
    for (int j = 0; j < 4; ++j) {
      int ng = n0 + wn * 64 + j * 16 + col;
#pragma unroll
      for (int r = 0; r < 4; ++r) out[(size_t)(mg + r) * N + ng] = acc[i][j][r];
    }
  }
}

// ---------------------------------------------------------------------------
// Flash attention, causal, paired q-tiles (uniform 34 kv-iters per block).
// Block (bh, p): phase0 = q-tile p (128 rows), phase1 = q-tile 15-p.
// 512 threads = 8 waves x 16 q rows. BC=64. Waves 0-3 stage K (contiguous),
// waves 4-7 stage tiled V^T (contiguous). LDS 48KB -> 2 blocks/CU, 16 waves.
// Grid (bh=64 fast, p=8): same-bh blocks land on one XCD under RR for L2 reuse.
// ---------------------------------------------------------------------------
__global__ __launch_bounds__(512, 4) void fattn(
    const u16* __restrict__ Qb, const u16* __restrict__ Kb, const u16* __restrict__ Vt,
    u16* __restrict__ Yb) {
  __shared__ alignas(16) u16 lK[64 * 128];    // [kc][d], chunk16 xor row&15
  __shared__ alignas(16) u16 lVt[128 * 64];   // [d][kc], chunk8 xor row&7
  __shared__ alignas(16) u16 lP[8][16 * 64];  // per-wave [qr][kc], chunk8 xor row&7

  const int tid = threadIdx.x;
  const int lane = tid & 63, wv = tid >> 6;    // 0..7
  const int quad = lane >> 4, col = lane & 15;
  const int bh = blockIdx.x;                   // fast dim -> XCD locality per bh
  const int p = blockIdx.y;                    // 0..7
  const int b = bh >> 4, h = bh & 15;
  const size_t base = (size_t)bh << 18;        // * 2048 * 128
  const float kcomb = 0.08838834764831845f * 1.4426950408889634f;  // 1/sqrt(D)*log2e

#pragma unroll 1
  for (int phase = 0; phase < 2; ++phase) {
    const int tq = phase ? (15 - p) : p;       // q-tile index (128 rows)
    const int qr0 = tq * 128 + wv * 16;        // wave's 16 q rows
    const int dkt = qr0 >> 6;                  // wave's diagonal kv-tile

    u16x8 qf[4];
#pragma unroll
    for (int t = 0; t < 4; ++t)
      qf[t] = *(const u16x8*)(Qb + base + (size_t)(qr0 + col) * 128 + t * 32 + quad * 8);

    f32x4 mrow = (f32x4){-1e30f, -1e30f, -1e30f, -1e30f};
    f32x4 lrow = (f32x4){0.f, 0.f, 0.f, 0.f};
    f32x4 o[8];
#pragma unroll
    for (int dt = 0; dt < 8; ++dt) o[dt] = (f32x4){0.f, 0.f, 0.f, 0.f};

    const int nkt = 2 * tq + 2;
#pragma unroll 1
    for (int kt = 0; kt < nkt; ++kt) {
      __syncthreads();
      if (wv < 4) {
        // stage K tile rows wv*16 .. +15 (contiguous 256B rows, swizzled chunks)
#pragma unroll
        for (int u = 0; u < 4; ++u) {
          int row = wv * 16 + u * 4 + (lane >> 4);
          int sc = (lane & 15) ^ (row & 15);
          gld_lds16(Kb + base + (size_t)(kt * 64 + row) * 128 + (sc << 3),
                    lK + (size_t)(wv * 16 + u * 4) * 128);
        }
      } else {
        // stage tiled V^T rows (wv-4)*32 .. +31 (contiguous 128B rows)
        int vw = wv - 4;
        const u16* vbase = Vt + ((size_t)(bh * 32 + kt) << 13);  // *128*64
#pragma unroll
        for (int u = 0; u < 4; ++u) {
          int row = vw * 32 + u * 8 + (lane >> 3);
          int sc = (lane & 7) ^ (row & 7);
          gld_lds16(vbase + (size_t)row * 64 + (sc << 3),
                    lVt + (size_t)(vw * 32 + u * 8) * 64);
        }
      }
      __syncthreads();

      if (kt <= dkt) {
        // QK^T
        f32x4 sv[4];
#pragma unroll
        for (int nt = 0; nt < 4; ++nt) {
          f32x4 s = (f32x4){0.f, 0.f, 0.f, 0.f};
#pragma unroll
          for (int t = 0; t < 4; ++t) {
            int krow = nt * 16 + col;
            u16x8 kf = *(const u16x8*)&lK[krow * 128 + ((((t << 2) | quad) ^ (krow & 15)) << 3)];
            s = MFMA16(qf[t], kf, s);
          }
          sv[nt] = s;
        }
#pragma unroll
        for (int nt = 0; nt < 4; ++nt)
#pragma unroll
          for (int r = 0; r < 4; ++r) sv[nt][r] *= kcomb;
        if (kt == dkt) {  // diagonal tile: causal mask
#pragma unroll
          for (int nt = 0; nt < 4; ++nt) {
            int cg = kt * 64 + nt * 16 + col;
#pragma unroll
            for (int r = 0; r < 4; ++r)
              if (cg > qr0 + quad * 4 + r) sv[nt][r] = -1e30f;
          }
        }
        // row max over nt and the 16 lanes holding this row
        f32x4 mx = sv[0];
#pragma unroll
        for (int nt = 1; nt < 4; ++nt)
#pragma unroll
          for (int r = 0; r < 4; ++r) mx[r] = fmaxf(mx[r], sv[nt][r]);
#pragma unroll
        for (int off = 1; off < 16; off <<= 1)
#pragma unroll
          for (int r = 0; r < 4; ++r) mx[r] = fmaxf(mx[r], __shfl_xor(mx[r], off));
        f32x4 alpha;
#pragma unroll
        for (int r = 0; r < 4; ++r) {
          float mn = fmaxf(mrow[r], mx[r]);
          alpha[r] = exp2f(mrow[r] - mn);
          mrow[r] = mn;
        }
        f32x4 ps = (f32x4){0.f, 0.f, 0.f, 0.f};
#pragma unroll
        for (int nt = 0; nt < 4; ++nt)
#pragma unroll
          for (int r = 0; r < 4; ++r) {
            float pe = exp2f(sv[nt][r] - mrow[r]);
            ps[r] += pe;
            int row = quad * 4 + r;
            int ch = ((nt << 1) | (col >> 3)) ^ (row & 7);
            lP[wv][row * 64 + (ch << 3) + (col & 7)] = f2b(pe);
          }
#pragma unroll
        for (int off = 1; off < 16; off <<= 1)
#pragma unroll
          for (int r = 0; r < 4; ++r) ps[r] += __shfl_xor(ps[r], off);
#pragma unroll
        for (int r = 0; r < 4; ++r) lrow[r] = lrow[r] * alpha[r] + ps[r];
#pragma unroll
        for (int dt = 0; dt < 8; ++dt)
#pragma unroll
          for (int r = 0; r < 4; ++r) o[dt][r] *= alpha[r];
        // PV: o += P(16x64) x V^T(64x128 as B-operand from lVt)
#pragma unroll
        for (int t = 0; t < 2; ++t) {
          u16x8 pf = *(const u16x8*)&lP[wv][col * 64 + ((((t << 2) | quad) ^ (col & 7)) << 3)];
#pragma unroll
          for (int dt = 0; dt < 8; ++dt) {
            int drow = dt * 16 + col;
            u16x8 vf = *(const u16x8*)&lVt[drow * 64 + ((((t << 2) | quad) ^ (drow & 7)) << 3)];
            o[dt] = MFMA16(pf, vf, o[dt]);
          }
        }
      }
    }  // kt

    // normalize + write Y (B*T, C) bf16
    f32x4 inv;
#pragma unroll
    for (int r = 0; r < 4; ++r) inv[r] = 1.0f / lrow[r];
#pragma unroll
    for (int dt = 0; dt < 8; ++dt)
#pragma unroll
      for (int r = 0; r < 4; ++r) {
        float y = o[dt][r] * inv[r];
        int q = qr0 + quad * 4 + r;
        Yb[((size_t)(b * 2048 + q)) * 2048 + h * 128 + dt * 16 + col] = f2b(y);
      }
  }  // phase
}

// ---------------------------------------------------------------------------
extern "C" void kernel_launch(void* const* d_in, const int* in_sizes, int n_in,
                              void* d_out, int out_size, void* d_ws, size_t ws_size,
                              hipStream_t stream) {
  (void)in_sizes; (void)n_in; (void)out_size; (void)ws_size;
  const float* x     = (const float*)d_in[0];
  const float* freqs = (const float*)d_in[1];
  const float* Wattn = (const float*)d_in[2];
  const float* Wproj = (const float*)d_in[3];
  float* out = (float*)d_out;
  char* ws = (char*)d_ws;

  u16* Wq_b = (u16*)(ws + 0);
  u16* Wp_b = (u16*)(ws + 25165824);
  u16* x_b  = (u16*)(ws + 33554432);
  u16* Qb   = (u16*)(ws + 67108864);
  u16* Kb   = (u16*)(ws + 100663296);
  u16* Vt   = (u16*)(ws + 134217728);
  u16* Yb   = (u16*)(ws + 167772160);

  cvt_bf16<<<6144, 256, 0, stream>>>((const float4*)Wattn, (u16x8*)Wq_b, 12582912 / 8);
  cvt_bf16<<<2048, 256, 0, stream>>>((const float4*)Wproj, (u16x8*)Wp_b, 4194304 / 8);
  cvt_bf16<<<8192, 256, 0, stream>>>((const float4*)x, (u16x8*)x_b, 16777216 / 8);

  gemm_qkv<<<dim3(48, 64), 256, 0, stream>>>(x_b, Wq_b, freqs, 2048, Qb, Kb, Vt);
  fattn<<<dim3(64, 8), 512, 0, stream>>>(Qb, Kb, Vt, Yb);
  gemm_proj<<<dim3(16, 64), 256, 0, stream>>>(Yb, Wp_b, 2048, 2048, out);
}